// Round 3
// baseline (811.961 us; speedup 1.0000x reference)
//
#include <hip/hip_runtime.h>
#include <hip/hip_bf16.h>
#include <stdint.h>

#define NN 8192
#define EE 32768
#define BB 256
#define DD 64
#define FIN 11
#define EIN 5
#define HH 128

typedef __attribute__((ext_vector_type(4))) float f32x4;
typedef __attribute__((ext_vector_type(8))) short bf16x8;

__device__ __forceinline__ float sigmoidf_(float x) { return 1.0f / (1.0f + expf(-x)); }

__device__ __forceinline__ void gload16(const void* g, void* l) {
    __builtin_amdgcn_global_load_lds(
        (const __attribute__((address_space(1))) unsigned int*)g,
        (__attribute__((address_space(3))) unsigned int*)l, 16, 0, 0);
}

// ---------------- permute nn2_w rows -> bf16: B'[f*64+d][k] = nn2_w[(d*64+f)][k] ----------------
__global__ __launch_bounds__(256) void k_permute(const float* __restrict__ nn2_w,
                                                 const float* __restrict__ nn2_b,
                                                 __hip_bfloat16* __restrict__ nn2P,
                                                 float* __restrict__ bP) {
    int idx = blockIdx.x * 256 + threadIdx.x;      // over 4096*128
    int j = idx >> 7, k = idx & 127;
    int d = j >> 6, f = j & 63;
    int jr = f * 64 + d;
    nn2P[(size_t)jr * 128 + k] = __float2bfloat16(nn2_w[idx]);
    if (k == 0) bP[jr] = nn2_b[j];
}

// ---------------- prepack Bcat = [root_w(64) ; gru_w_hh(192)], bcat = [0 ; gru_b_hh] ----------------
__global__ __launch_bounds__(256) void k_prep(const float* __restrict__ root_w,
                                              const float* __restrict__ whh,
                                              const float* __restrict__ bhh,
                                              float* __restrict__ Bcat,
                                              float* __restrict__ bcat) {
    int i = blockIdx.x * 256 + threadIdx.x;        // over 256*64
    int r = i >> 6, c = i & 63;
    Bcat[i] = (r < 64) ? root_w[i] : whh[(size_t)(r - 64) * 64 + c];
    if (c == 0) bcat[r] = (r < 64) ? 0.0f : bhh[r - 64];
}

// ---------------- lin0 ----------------
__global__ __launch_bounds__(256) void k_lin0(const float* __restrict__ x,
                                              const float* __restrict__ w,
                                              const float* __restrict__ b,
                                              float* __restrict__ out) {
    int idx = blockIdx.x * 256 + threadIdx.x;      // over N*64
    int n = idx >> 6, d = idx & 63;
    float a = b[d];
#pragma unroll
    for (int k = 0; k < FIN; k++) a += x[n * FIN + k] * w[d * FIN + k];
    out[idx] = fmaxf(a, 0.0f);
}

// ---------------- h1 -> bf16 ----------------
__global__ __launch_bounds__(256) void k_h1(const float* __restrict__ ea,
                                            const float* __restrict__ w,
                                            const float* __restrict__ b,
                                            __hip_bfloat16* __restrict__ h1) {
    int idx = blockIdx.x * 256 + threadIdx.x;      // over E*128
    int e = idx >> 7, k = idx & 127;
    float a = b[k];
#pragma unroll
    for (int j = 0; j < EIN; j++) a += ea[e * EIN + j] * w[k * EIN + j];
    h1[idx] = __float2bfloat16(fmaxf(a, 0.0f));
}

// ---------------- degree ----------------
__global__ __launch_bounds__(256) void k_count(const int* __restrict__ ei, int* __restrict__ deg) {
    int e = blockIdx.x * 256 + threadIdx.x;
    if (e < EE) atomicAdd(&deg[ei[EE + e]], 1);
}
__global__ __launch_bounds__(256) void k_inv(const int* __restrict__ deg, float* __restrict__ invd) {
    int n = blockIdx.x * 256 + threadIdx.x;
    if (n < NN) { int d = deg[n]; invd[n] = d > 0 ? 1.0f / (float)d : 0.0f; }
}

// ---------------- fused NNConv message pass ----------------
// Tile: 64 edges (by) x 128 W-cols (bx; col jr = f*64+d, so 2 f per block, 1 per wave).
// MFMA computes W chunk in f32 regs; multiply by staged out[src], reduce over d,
// atomicAdd inv_deg-scaled into agg[dst, f]. W_e never materialized.
__global__ __launch_bounds__(256) void k_wemsg(const __hip_bfloat16* __restrict__ h1,
                                               const __hip_bfloat16* __restrict__ nn2P,
                                               const float* __restrict__ bP,
                                               const float* __restrict__ outN,
                                               const int* __restrict__ ei,
                                               const float* __restrict__ invd,
                                               float* __restrict__ agg) {
    __shared__ ushort sA[64 * 128];    // 16 KB  h1 tile (swizzled)
    __shared__ ushort sB[128 * 128];   // 32 KB  nn2P tile (swizzled)
    __shared__ float so[64][68];       // out rows for the 64 edges (stride 68: 2-way max)
    __shared__ int sDst[64];
    __shared__ float sIv[64];

    const int t = threadIdx.x;
    const int w = t >> 6, l = t & 63;
    const int q = l >> 4, l15 = l & 15;
    const int bx = blockIdx.x, by = blockIdx.y;
    const int e0 = by * 64;

    // gather out[src] rows + edge meta
    {
        int r = t >> 2, dq = (t & 3) * 16;
        int s_ = ei[e0 + r];
        const float4* op = (const float4*)(outN + (size_t)s_ * 64 + dq);
        float4 v0 = op[0], v1 = op[1], v2 = op[2], v3 = op[3];
        *(float4*)&so[r][dq + 0] = v0;
        *(float4*)&so[r][dq + 4] = v1;
        *(float4*)&so[r][dq + 8] = v2;
        *(float4*)&so[r][dq + 12] = v3;
        if ((t & 3) == 0) {
            int d_ = ei[EE + e0 + r];
            sDst[r] = d_;
            sIv[r] = invd[d_];
        }
    }
    // stage A (h1 rows e0..e0+63): 1024 16B-units, inverse-swizzled source
#pragma unroll
    for (int i = 0; i < 4; i++) {
        int u = i * 256 + w * 64 + l;
        int r = u >> 4, c = u & 15, cs = c ^ (r & 7);
        gload16(h1 + ((size_t)(e0 + r) * 128 + cs * 8), &sA[(i * 256 + w * 64) * 8]);
    }
    // stage B (nn2P rows bx*128..+127): 2048 units
#pragma unroll
    for (int i = 0; i < 8; i++) {
        int u = i * 256 + w * 64 + l;
        int r = u >> 4, c = u & 15, cs = c ^ (r & 7);
        gload16(nn2P + ((size_t)(bx * 128 + r) * 128 + cs * 8), &sB[(i * 256 + w * 64) * 8]);
    }
    __syncthreads();

    const int wrow = w >> 1, wcol = w & 1;         // edge-half, f-half
    f32x4 acc[2][4];
#pragma unroll
    for (int i = 0; i < 2; i++)
#pragma unroll
        for (int j = 0; j < 4; j++) acc[i][j] = (f32x4)0.0f;

#pragma unroll
    for (int kk = 0; kk < 4; kk++) {
        const int u16 = kk * 4 + q;
        bf16x8 af[2], bfr[4];
#pragma unroll
        for (int mi = 0; mi < 2; mi++) {
            int r = wrow * 32 + mi * 16 + l15;
            af[mi] = *(const bf16x8*)&sA[(r * 16 + (u16 ^ (r & 7))) * 8];
        }
#pragma unroll
        for (int ni = 0; ni < 4; ni++) {
            int rb = wcol * 64 + ni * 16 + l15;
            bfr[ni] = *(const bf16x8*)&sB[(rb * 16 + (u16 ^ (rb & 7))) * 8];
        }
#pragma unroll
        for (int mi = 0; mi < 2; mi++)
#pragma unroll
            for (int ni = 0; ni < 4; ni++)
                acc[mi][ni] = __builtin_amdgcn_mfma_f32_16x16x32_bf16(af[mi], bfr[ni], acc[mi][ni], 0, 0, 0);
    }

    // reduce over d and scatter
    float bv[4];
#pragma unroll
    for (int ni = 0; ni < 4; ni++) bv[ni] = bP[bx * 128 + wcol * 64 + ni * 16 + l15];
    const int fcol = bx * 2 + wcol;
#pragma unroll
    for (int mi = 0; mi < 2; mi++) {
#pragma unroll
        for (int j = 0; j < 4; j++) {
            int r = wrow * 32 + mi * 16 + q * 4 + j;
            float p = (acc[mi][0][j] + bv[0]) * so[r][l15]
                    + (acc[mi][1][j] + bv[1]) * so[r][16 + l15]
                    + (acc[mi][2][j] + bv[2]) * so[r][32 + l15]
                    + (acc[mi][3][j] + bv[3]) * so[r][48 + l15];
            p += __shfl_xor(p, 1, 64);
            p += __shfl_xor(p, 2, 64);
            p += __shfl_xor(p, 4, 64);
            p += __shfl_xor(p, 8, 64);
            if (l15 == 0) atomicAdd(&agg[(size_t)sDst[r] * 64 + fcol], p * sIv[r]);
        }
    }
}

// ---------------- f32 tiled GEMM: C[row,col] = A[row,:64].Bm[col,:64] (+bias) ----------------
template <int K>
__global__ __launch_bounds__(256) void k_gemm(const float* __restrict__ A,
                                              const float* __restrict__ Bm,
                                              const float* __restrict__ bias,
                                              float* __restrict__ C, int ldc) {
    __shared__ float sA[64 * 68];
    __shared__ float sB[64 * 68];
    const int tid = threadIdx.x;
    const int bx = blockIdx.x, by = blockIdx.y;
    const float* Ab = A + (size_t)by * 64 * K;
    const float* Bb = Bm + (size_t)bx * 64 * K;
    const int k4 = K >> 2;
    for (int fi = tid; fi < 64 * k4; fi += 256) {
        int r = fi / k4, c = fi % k4;
        float4 av = reinterpret_cast<const float4*>(Ab + (size_t)r * K)[c];
        *reinterpret_cast<float4*>(&sA[r * 68 + c * 4]) = av;
        float4 bv = reinterpret_cast<const float4*>(Bb + (size_t)r * K)[c];
        *reinterpret_cast<float4*>(&sB[r * 68 + c * 4]) = bv;
    }
    __syncthreads();
    const int tx = tid & 15, ty = tid >> 4;
    float acc[4][4];
#pragma unroll
    for (int i = 0; i < 4; i++)
#pragma unroll
        for (int j = 0; j < 4; j++) acc[i][j] = 0.0f;
    for (int k = 0; k < K; k += 4) {
        float4 av[4], bv[4];
#pragma unroll
        for (int i = 0; i < 4; i++) av[i] = *reinterpret_cast<const float4*>(&sA[(ty + 16 * i) * 68 + k]);
#pragma unroll
        for (int j = 0; j < 4; j++) bv[j] = *reinterpret_cast<const float4*>(&sB[(tx + 16 * j) * 68 + k]);
#pragma unroll
        for (int i = 0; i < 4; i++)
#pragma unroll
            for (int j = 0; j < 4; j++) {
                acc[i][j] += av[i].x * bv[j].x;
                acc[i][j] += av[i].y * bv[j].y;
                acc[i][j] += av[i].z * bv[j].z;
                acc[i][j] += av[i].w * bv[j].w;
            }
    }
#pragma unroll
    for (int i = 0; i < 4; i++) {
        size_t row = (size_t)by * 64 + ty + 16 * i;
#pragma unroll
        for (int j = 0; j < 4; j++) {
            int col = bx * 64 + tx + 16 * j;
            float v = acc[i][j];
            if (bias) v += bias[col];
            C[row * ldc + col] = v;
        }
    }
}

// ---------------- gx GEMM with fused m = relu(agg + rootC + conv_b) in A-staging ----------------
__global__ __launch_bounds__(256) void k_gx(const float* __restrict__ agg,
                                            const float* __restrict__ rgh,
                                            const float* __restrict__ cb,
                                            const float* __restrict__ Bm,
                                            const float* __restrict__ bias,
                                            float* __restrict__ C) {
    __shared__ float sA[64 * 68];
    __shared__ float sB[64 * 68];
    const int tid = threadIdx.x;
    const int bx = blockIdx.x, by = blockIdx.y;
    for (int fi = tid; fi < 64 * 16; fi += 256) {
        int r = fi >> 4, c = (fi & 15) * 4;
        float4 av = *(const float4*)(agg + (size_t)(by * 64 + r) * 64 + c);
        float4 rv = *(const float4*)(rgh + (size_t)(by * 64 + r) * 256 + c);
        float4 cv = *(const float4*)(cb + c);
        float4 m;
        m.x = fmaxf(av.x + rv.x + cv.x, 0.0f);
        m.y = fmaxf(av.y + rv.y + cv.y, 0.0f);
        m.z = fmaxf(av.z + rv.z + cv.z, 0.0f);
        m.w = fmaxf(av.w + rv.w + cv.w, 0.0f);
        *(float4*)&sA[r * 68 + c] = m;
    }
    for (int fi = tid; fi < 64 * 16; fi += 256) {
        int r = fi >> 4, c = (fi & 15) * 4;
        *(float4*)&sB[r * 68 + c] = *(const float4*)(Bm + (size_t)(bx * 64 + r) * 64 + c);
    }
    __syncthreads();
    const int tx = tid & 15, ty = tid >> 4;
    float acc[4][4];
#pragma unroll
    for (int i = 0; i < 4; i++)
#pragma unroll
        for (int j = 0; j < 4; j++) acc[i][j] = 0.0f;
    for (int k = 0; k < 64; k += 4) {
        float4 av[4], bv[4];
#pragma unroll
        for (int i = 0; i < 4; i++) av[i] = *reinterpret_cast<const float4*>(&sA[(ty + 16 * i) * 68 + k]);
#pragma unroll
        for (int j = 0; j < 4; j++) bv[j] = *reinterpret_cast<const float4*>(&sB[(tx + 16 * j) * 68 + k]);
#pragma unroll
        for (int i = 0; i < 4; i++)
#pragma unroll
            for (int j = 0; j < 4; j++) {
                acc[i][j] += av[i].x * bv[j].x;
                acc[i][j] += av[i].y * bv[j].y;
                acc[i][j] += av[i].z * bv[j].z;
                acc[i][j] += av[i].w * bv[j].w;
            }
    }
#pragma unroll
    for (int i = 0; i < 4; i++) {
        size_t row = (size_t)by * 64 + ty + 16 * i;
#pragma unroll
        for (int j = 0; j < 4; j++) {
            int col = bx * 64 + tx + 16 * j;
            C[row * 192 + col] = acc[i][j] + bias[col];
        }
    }
}

// ---------------- GRU elementwise (gh lives in rgh cols 64..255) ----------------
__global__ __launch_bounds__(256) void k_gru(const float* __restrict__ gx,
                                             const float* __restrict__ rgh,
                                             float* __restrict__ out) {
    int idx = blockIdx.x * 256 + threadIdx.x;
    int n = idx >> 6, d = idx & 63;
    const float* gxr = gx + (size_t)n * 192;
    const float* ghr = rgh + (size_t)n * 256 + 64;
    float r = sigmoidf_(gxr[d] + ghr[d]);
    float z = sigmoidf_(gxr[64 + d] + ghr[64 + d]);
    float nn_ = tanhf(gxr[128 + d] + r * ghr[128 + d]);
    float hp = out[idx];
    out[idx] = (1.0f - z) * nn_ + z * hp;
}

// ---------------- batch counting + scan ----------------
__global__ __launch_bounds__(256) void k_cntbatch(const int* __restrict__ batch, int* __restrict__ cnt) {
    int n = blockIdx.x * 256 + threadIdx.x;
    if (n < NN) atomicAdd(&cnt[batch[n]], 1);
}
__global__ __launch_bounds__(256) void k_scan(const int* __restrict__ cnt, int* __restrict__ offs) {
    __shared__ int s[256];
    int t = threadIdx.x;
    s[t] = cnt[t];
    __syncthreads();
    for (int off = 1; off < 256; off <<= 1) {
        int v = (t >= off) ? s[t - off] : 0;
        __syncthreads();
        s[t] += v;
        __syncthreads();
    }
    offs[t + 1] = s[t];
    if (t == 0) offs[0] = 0;
}

// ---------------- Set2Set LSTM step ----------------
__global__ __launch_bounds__(256) void k_s2s(const float* __restrict__ qstar,
                                             float* __restrict__ qh, float* __restrict__ qc,
                                             const float* __restrict__ wih, const float* __restrict__ whh,
                                             const float* __restrict__ bih, const float* __restrict__ bhh) {
    int b = blockIdx.x, j = threadIdx.x;
    float g = bih[j] + bhh[j];
    const float* qs = qstar + (size_t)b * 128;
    const float* qhr = qh + (size_t)b * 64;
    for (int k = 0; k < 128; k++) g += qs[k] * wih[j * 128 + k];
    for (int k = 0; k < 64; k++) g += qhr[k] * whh[j * 64 + k];
    __shared__ float sg[256];
    sg[j] = g;
    __syncthreads();
    if (j < 64) {
        float gi = sg[j], gf = sg[64 + j], gg = sg[128 + j], go = sg[192 + j];
        float c = sigmoidf_(gf) * qc[b * 64 + j] + sigmoidf_(gi) * tanhf(gg);
        float h = sigmoidf_(go) * tanhf(c);
        qc[b * 64 + j] = c;
        qh[b * 64 + j] = h;
    }
}

// ---------------- e[n] = dot(out[n,:], qh[batch[n],:]) ----------------
__global__ __launch_bounds__(256) void k_e(const float* __restrict__ out,
                                           const float* __restrict__ qh,
                                           const int* __restrict__ batch,
                                           float* __restrict__ earr) {
    int n = blockIdx.x * 4 + (threadIdx.x >> 6);
    int lane = threadIdx.x & 63;
    float p = out[(size_t)n * 64 + lane] * qh[(size_t)batch[n] * 64 + lane];
#pragma unroll
    for (int o = 32; o > 0; o >>= 1) p += __shfl_xor(p, o, 64);
    if (lane == 0) earr[n] = p;
}

// ---------------- per-graph softmax + weighted sum -> q_star ----------------
__global__ __launch_bounds__(64) void k_seg(const int* __restrict__ offs,
                                            const float* __restrict__ earr,
                                            const float* __restrict__ out,
                                            const float* __restrict__ qh,
                                            float* __restrict__ qstar) {
    int b = blockIdx.x, lane = threadIdx.x;
    int s0 = offs[b], s1 = offs[b + 1];
    float mx = -INFINITY;
    for (int i = s0 + lane; i < s1; i += 64) mx = fmaxf(mx, earr[i]);
#pragma unroll
    for (int o = 32; o > 0; o >>= 1) mx = fmaxf(mx, __shfl_xor(mx, o, 64));
    if (!isfinite(mx)) mx = 0.0f;
    float sm = 0.0f;
    for (int i = s0 + lane; i < s1; i += 64) sm += expf(earr[i] - mx);
#pragma unroll
    for (int o = 32; o > 0; o >>= 1) sm += __shfl_xor(sm, o, 64);
    float r = 0.0f;
    for (int i = s0; i < s1; i++) r += expf(earr[i] - mx) * out[(size_t)i * 64 + lane];
    r /= fmaxf(sm, 1e-12f);
    qstar[(size_t)b * 128 + 64 + lane] = r;
    qstar[(size_t)b * 128 + lane] = qh[(size_t)b * 64 + lane];
}

// ---------------- head ----------------
__global__ __launch_bounds__(64) void k_final(const float* __restrict__ qstar,
                                              const float* __restrict__ w1, const float* __restrict__ b1,
                                              const float* __restrict__ w2, const float* __restrict__ b2,
                                              float* __restrict__ y) {
    int b = blockIdx.x, j = threadIdx.x;
    float h = b1[j];
    const float* qs = qstar + (size_t)b * 128;
    for (int k = 0; k < 128; k++) h += qs[k] * w1[j * 128 + k];
    h = fmaxf(h, 0.0f);
    float p = h * w2[j];
#pragma unroll
    for (int o = 32; o > 0; o >>= 1) p += __shfl_xor(p, o, 64);
    if (j == 0) y[b] = p + b2[0];
}

extern "C" void kernel_launch(void* const* d_in, const int* in_sizes, int n_in,
                              void* d_out, int out_size, void* d_ws, size_t ws_size,
                              hipStream_t stream) {
    const float* x = (const float*)d_in[0];
    const float* edge_attr = (const float*)d_in[1];
    const float* lin0_w = (const float*)d_in[2];
    const float* lin0_b = (const float*)d_in[3];
    const float* nn1_w = (const float*)d_in[4];
    const float* nn1_b = (const float*)d_in[5];
    const float* nn2_w = (const float*)d_in[6];
    const float* nn2_b = (const float*)d_in[7];
    const float* root_w = (const float*)d_in[8];
    const float* conv_b = (const float*)d_in[9];
    const float* gru_w_ih = (const float*)d_in[10];
    const float* gru_w_hh = (const float*)d_in[11];
    const float* gru_b_ih = (const float*)d_in[12];
    const float* gru_b_hh = (const float*)d_in[13];
    const float* s2s_w_ih = (const float*)d_in[14];
    const float* s2s_w_hh = (const float*)d_in[15];
    const float* s2s_b_ih = (const float*)d_in[16];
    const float* s2s_b_hh = (const float*)d_in[17];
    const float* lin1_w = (const float*)d_in[18];
    const float* lin1_b = (const float*)d_in[19];
    const float* lin2_w = (const float*)d_in[20];
    const float* lin2_b = (const float*)d_in[21];
    const int* ei = (const int*)d_in[22];
    const int* batch = (const int*)d_in[23];
    float* outp = (float*)d_out;

    char* w = (char*)d_ws;
    auto carve = [&](size_t bytes) { char* p = w; w += (bytes + 255) & ~(size_t)255; return p; };
    __hip_bfloat16* nn2P = (__hip_bfloat16*)carve((size_t)4096 * 128 * 2);
    float* bP = (float*)carve(4096 * 4);
    float* outN = (float*)carve((size_t)NN * 64 * 4);
    __hip_bfloat16* h1 = (__hip_bfloat16*)carve((size_t)EE * 128 * 2);
    int* deg = (int*)carve(NN * 4);
    float* invd = (float*)carve(NN * 4);
    float* agg = (float*)carve((size_t)NN * 64 * 4);
    float* rgh = (float*)carve((size_t)NN * 256 * 4);
    float* gx = (float*)carve((size_t)NN * 192 * 4);
    float* Bcat = (float*)carve((size_t)256 * 64 * 4);
    float* bcat = (float*)carve(256 * 4);
    float* earr = (float*)carve(NN * 4);
    int* cnt = (int*)carve(256 * 4);
    int* offs = (int*)carve(257 * 4);
    float* qh = (float*)carve((size_t)BB * 64 * 4);
    float* qc = (float*)carve((size_t)BB * 64 * 4);
    float* qstar = (float*)carve((size_t)BB * 128 * 4);

    hipMemsetAsync(deg, 0, NN * 4, stream);
    hipMemsetAsync(cnt, 0, 256 * 4, stream);
    hipMemsetAsync(qh, 0, BB * 64 * 4, stream);
    hipMemsetAsync(qc, 0, BB * 64 * 4, stream);
    hipMemsetAsync(qstar, 0, BB * 128 * 4, stream);

    k_permute<<<2048, 256, 0, stream>>>(nn2_w, nn2_b, nn2P, bP);
    k_prep<<<64, 256, 0, stream>>>(root_w, gru_w_hh, gru_b_hh, Bcat, bcat);
    k_lin0<<<NN * 64 / 256, 256, 0, stream>>>(x, lin0_w, lin0_b, outN);
    k_h1<<<EE * 128 / 256, 256, 0, stream>>>(edge_attr, nn1_w, nn1_b, h1);
    k_count<<<EE / 256, 256, 0, stream>>>(ei, deg);
    k_inv<<<NN / 256, 256, 0, stream>>>(deg, invd);
    k_cntbatch<<<NN / 256, 256, 0, stream>>>(batch, cnt);
    k_scan<<<1, 256, 0, stream>>>(cnt, offs);

    for (int it = 0; it < 3; it++) {
        hipMemsetAsync(agg, 0, (size_t)NN * 64 * 4, stream);
        // rgh = [rootC | gh] = outN @ Bcat.T (+bcat) — independent of agg
        k_gemm<64><<<dim3(4, NN / 64), 256, 0, stream>>>(outN, Bcat, bcat, rgh, 256);
        k_wemsg<<<dim3(32, EE / 64), 256, 0, stream>>>(h1, nn2P, bP, outN, ei, invd, agg);
        k_gx<<<dim3(3, NN / 64), 256, 0, stream>>>(agg, rgh, conv_b, gru_w_ih, gru_b_ih, gx);
        k_gru<<<NN * 64 / 256, 256, 0, stream>>>(gx, rgh, outN);
    }

    for (int st = 0; st < 3; st++) {
        k_s2s<<<BB, 256, 0, stream>>>(qstar, qh, qc, s2s_w_ih, s2s_w_hh, s2s_b_ih, s2s_b_hh);
        k_e<<<NN / 4, 256, 0, stream>>>(outN, qh, batch, earr);
        k_seg<<<BB, 64, 0, stream>>>(offs, earr, outN, qh, qstar);
    }
    k_final<<<BB, 64, 0, stream>>>(qstar, lin1_w, lin1_b, lin2_w, lin2_b, outp);
}

// Round 4
// 379.311 us; speedup vs baseline: 2.1406x; 2.1406x over previous
//
#include <hip/hip_runtime.h>
#include <hip/hip_bf16.h>
#include <stdint.h>

#define NN 8192
#define EE 32768
#define BB 256
#define DD 64
#define FIN 11
#define EIN 5
#define HH 128

typedef __attribute__((ext_vector_type(4))) float f32x4;
typedef __attribute__((ext_vector_type(8))) short bf16x8;

__device__ __forceinline__ float sigmoidf_(float x) { return 1.0f / (1.0f + expf(-x)); }

__device__ __forceinline__ void gload16(const void* g, void* l) {
    __builtin_amdgcn_global_load_lds(
        (const __attribute__((address_space(1))) unsigned int*)g,
        (__attribute__((address_space(3))) unsigned int*)l, 16, 0, 0);
}

// ---------------- cast nn2_w -> bf16 (natural layout [j=d*64+f][k]) ----------------
__global__ __launch_bounds__(256) void k_cast(const float* __restrict__ src,
                                              __hip_bfloat16* __restrict__ dst) {
    int i = (blockIdx.x * 256 + threadIdx.x) * 4;     // over 4096*128
    float4 v = *(const float4*)(src + i);
    ushort4 o;
    __hip_bfloat16 b0 = __float2bfloat16(v.x); o.x = *(ushort*)&b0;
    __hip_bfloat16 b1 = __float2bfloat16(v.y); o.y = *(ushort*)&b1;
    __hip_bfloat16 b2 = __float2bfloat16(v.z); o.z = *(ushort*)&b2;
    __hip_bfloat16 b3 = __float2bfloat16(v.w); o.w = *(ushort*)&b3;
    *(ushort4*)((ushort*)dst + i) = o;
}

// ---------------- prepack Bcat = [root_w(64) ; gru_w_hh(192)], bcat = [0 ; gru_b_hh] ----------------
__global__ __launch_bounds__(256) void k_prep(const float* __restrict__ root_w,
                                              const float* __restrict__ whh,
                                              const float* __restrict__ bhh,
                                              float* __restrict__ Bcat,
                                              float* __restrict__ bcat) {
    int i = blockIdx.x * 256 + threadIdx.x;           // over 256*64
    int r = i >> 6, c = i & 63;
    Bcat[i] = (r < 64) ? root_w[i] : whh[(size_t)(r - 64) * 64 + c];
    if (c == 0) bcat[r] = (r < 64) ? 0.0f : bhh[r - 64];
}

// ---------------- transpose s2s weights: wihT[k][j]=wih[j][k], whhT[k][j]=whh[j][k] ----------------
__global__ __launch_bounds__(256) void k_tw(const float* __restrict__ wih,
                                            const float* __restrict__ whh,
                                            float* __restrict__ wihT,
                                            float* __restrict__ whhT) {
    int i = blockIdx.x * 256 + threadIdx.x;           // 32768 + 16384
    if (i < 256 * 128) {
        int j = i >> 7, k = i & 127;
        wihT[k * 256 + j] = wih[i];
    } else {
        int i2 = i - 256 * 128;
        if (i2 < 256 * 64) {
            int j = i2 >> 6, k = i2 & 63;
            whhT[k * 256 + j] = whh[i2];
        }
    }
}

// ---------------- lin0 ----------------
__global__ __launch_bounds__(256) void k_lin0(const float* __restrict__ x,
                                              const float* __restrict__ w,
                                              const float* __restrict__ b,
                                              float* __restrict__ out) {
    int idx = blockIdx.x * 256 + threadIdx.x;         // over N*64
    int n = idx >> 6, d = idx & 63;
    float a = b[d];
#pragma unroll
    for (int k = 0; k < FIN; k++) a += x[n * FIN + k] * w[d * FIN + k];
    out[idx] = fmaxf(a, 0.0f);
}

// ---------------- h1 -> bf16 ----------------
__global__ __launch_bounds__(256) void k_h1(const float* __restrict__ ea,
                                            const float* __restrict__ w,
                                            const float* __restrict__ b,
                                            __hip_bfloat16* __restrict__ h1) {
    int idx = blockIdx.x * 256 + threadIdx.x;         // over E*128
    int e = idx >> 7, k = idx & 127;
    float a = b[k];
#pragma unroll
    for (int j = 0; j < EIN; j++) a += ea[e * EIN + j] * w[k * EIN + j];
    h1[idx] = __float2bfloat16(fmaxf(a, 0.0f));
}

// ---------------- degree count + batch count (merged) ----------------
__global__ __launch_bounds__(256) void k_counts(const int* __restrict__ ei,
                                                const int* __restrict__ batch,
                                                int* __restrict__ deg,
                                                int* __restrict__ cnt) {
    int i = blockIdx.x * 256 + threadIdx.x;
    if (i < EE) atomicAdd(&deg[ei[EE + i]], 1);
    if (i < NN) atomicAdd(&cnt[batch[i]], 1);
}
__global__ __launch_bounds__(256) void k_inv(const int* __restrict__ deg, float* __restrict__ invd) {
    int n = blockIdx.x * 256 + threadIdx.x;
    if (n < NN) { int d = deg[n]; invd[n] = d > 0 ? 1.0f / (float)d : 0.0f; }
}
__global__ __launch_bounds__(256) void k_scan(const int* __restrict__ cnt, int* __restrict__ offs) {
    __shared__ int s[256];
    int t = threadIdx.x;
    s[t] = cnt[t];
    __syncthreads();
    for (int off = 1; off < 256; off <<= 1) {
        int v = (t >= off) ? s[t - off] : 0;
        __syncthreads();
        s[t] += v;
        __syncthreads();
    }
    offs[t + 1] = s[t];
    if (t == 0) offs[0] = 0;
}

// ---------------- fused NNConv message pass, d-major ----------------
// Block = 64 edges. Loop 32 chunks of nn2 rows j=bx*128..+127 (j=d*64+f -> 2 d x 64 f).
// MFMA gives Wchunk[e, c]; cols c<64 -> d0=2bx, f=c; c>=64 -> d1. msg[e][f] accumulates
// in registers via per-lane FMA with broadcast so[e][d]. One coalesced atomic scatter at end.
__global__ __launch_bounds__(256) void k_wemsg(const __hip_bfloat16* __restrict__ h1,
                                               const __hip_bfloat16* __restrict__ nn2bf,
                                               const float* __restrict__ nn2b,
                                               const float* __restrict__ outN,
                                               const int* __restrict__ ei,
                                               const float* __restrict__ invd,
                                               float* __restrict__ agg) {
    __shared__ ushort sA[64 * 128];    // 16 KB h1 tile (swizzled)
    __shared__ ushort sB[128 * 128];   // 32 KB nn2 chunk (swizzled)
    __shared__ float so[64][68];       // 17 KB out[src] rows
    __shared__ float sBias[128];
    __shared__ int sDst[64];
    __shared__ float sIv[64];

    const int t = threadIdx.x;
    const int w = t >> 6, l = t & 63;
    const int q = l >> 4, l15 = l & 15;
    const int e0 = blockIdx.x * 64;

    // gather out[src] rows + edge meta
    {
        int r = t >> 2, dq = (t & 3) * 16;
        int s_ = ei[e0 + r];
        const float4* op = (const float4*)(outN + (size_t)s_ * 64 + dq);
        float4 v0 = op[0], v1 = op[1], v2 = op[2], v3 = op[3];
        *(float4*)&so[r][dq + 0] = v0;
        *(float4*)&so[r][dq + 4] = v1;
        *(float4*)&so[r][dq + 8] = v2;
        *(float4*)&so[r][dq + 12] = v3;
        if ((t & 3) == 0) {
            int d_ = ei[EE + e0 + r];
            sDst[r] = d_;
            sIv[r] = invd[d_];
        }
    }
    // stage A (h1 rows e0..e0+63) once: 1024 16B-units, inverse-swizzled source
#pragma unroll
    for (int i = 0; i < 4; i++) {
        int u = i * 256 + t;
        int r = u >> 4, c = u & 15, cs = c ^ (r & 7);
        gload16(h1 + ((size_t)(e0 + r) * 128 + cs * 8), &sA[(i * 256 + w * 64) * 8]);
    }

    float msg[4][4];
#pragma unroll
    for (int j = 0; j < 4; j++)
#pragma unroll
        for (int f = 0; f < 4; f++) msg[j][f] = 0.0f;

    for (int bx = 0; bx < 32; ++bx) {
        __syncthreads();   // previous chunk fully consumed (also covers initial staging)
        // stage B chunk: rows bx*128..+127, 2048 units
#pragma unroll
        for (int i = 0; i < 8; i++) {
            int u = i * 256 + t;
            int r = u >> 4, c = u & 15, cs = c ^ (r & 7);
            gload16(nn2bf + ((size_t)(bx * 128 + r) * 128 + cs * 8), &sB[(i * 256 + w * 64) * 8]);
        }
        if (t < 32) *(float4*)&sBias[t * 4] = *(const float4*)(nn2b + bx * 128 + t * 4);
        __syncthreads();   // staging complete (vmcnt drained)

        f32x4 acc[8];
#pragma unroll
        for (int ni = 0; ni < 8; ni++) acc[ni] = (f32x4)0.0f;
#pragma unroll
        for (int kk = 0; kk < 4; kk++) {
            const int u16 = kk * 4 + q;
            const int ra = w * 16 + l15;
            bf16x8 af = *(const bf16x8*)&sA[(ra * 16 + (u16 ^ (ra & 7))) * 8];
#pragma unroll
            for (int ni = 0; ni < 8; ni++) {
                int rb = ni * 16 + l15;
                bf16x8 bfr = *(const bf16x8*)&sB[(rb * 16 + (u16 ^ (rb & 7))) * 8];
                acc[ni] = __builtin_amdgcn_mfma_f32_16x16x32_bf16(af, bfr, acc[ni], 0, 0, 0);
            }
        }
        // fold chunk into msg registers (bias included here, summed over chunks = full bias once)
        float bb0[4], bb1[4];
#pragma unroll
        for (int f = 0; f < 4; f++) {
            bb0[f] = sBias[f * 16 + l15];
            bb1[f] = sBias[64 + f * 16 + l15];
        }
        const int d0 = bx * 2, d1 = d0 + 1;
#pragma unroll
        for (int j = 0; j < 4; j++) {
            int er = w * 16 + q * 4 + j;
            float s0v = so[er][d0], s1v = so[er][d1];
#pragma unroll
            for (int f = 0; f < 4; f++)
                msg[j][f] += (acc[f][j] + bb0[f]) * s0v + (acc[f + 4][j] + bb1[f]) * s1v;
        }
    }
    // scatter: lane (q,l15) of wave w holds msg for e=w*16+q*4+j, f=f*16+l15
#pragma unroll
    for (int j = 0; j < 4; j++) {
        int er = w * 16 + q * 4 + j;
        int dst = sDst[er];
        float iv = sIv[er];
#pragma unroll
        for (int f = 0; f < 4; f++)
            atomicAdd(&agg[(size_t)dst * 64 + f * 16 + l15], msg[j][f] * iv);
    }
}

// ---------------- rgh = outN @ Bcat.T + bcat  (also zeroes agg slice) ----------------
__global__ __launch_bounds__(256) void k_rgh(const float* __restrict__ A,
                                             const float* __restrict__ Bm,
                                             const float* __restrict__ bias,
                                             float* __restrict__ C,
                                             float* __restrict__ aggz) {
    const int tid = threadIdx.x;
    const int bx = blockIdx.x, by = blockIdx.y;
    {   // zero 1024 floats of agg per block (512 blocks x 1024 = 512K = full agg)
        int bid = by * 4 + bx;
        float4 z; z.x = z.y = z.z = z.w = 0.0f;
        *(float4*)(aggz + (size_t)bid * 1024 + tid * 4) = z;
    }
    __shared__ float sA[64 * 68];
    __shared__ float sB[64 * 68];
    const float* Ab = A + (size_t)by * 64 * 64;
    const float* Bb = Bm + (size_t)bx * 64 * 64;
    for (int fi = tid; fi < 64 * 16; fi += 256) {
        int r = fi >> 4, c = (fi & 15) * 4;
        *(float4*)&sA[r * 68 + c] = *(const float4*)(Ab + (size_t)r * 64 + c);
        *(float4*)&sB[r * 68 + c] = *(const float4*)(Bb + (size_t)r * 64 + c);
    }
    __syncthreads();
    const int tx = tid & 15, ty = tid >> 4;
    float acc[4][4];
#pragma unroll
    for (int i = 0; i < 4; i++)
#pragma unroll
        for (int j = 0; j < 4; j++) acc[i][j] = 0.0f;
    for (int k = 0; k < 64; k += 4) {
        float4 av[4], bv[4];
#pragma unroll
        for (int i = 0; i < 4; i++) av[i] = *(const float4*)&sA[(ty + 16 * i) * 68 + k];
#pragma unroll
        for (int j = 0; j < 4; j++) bv[j] = *(const float4*)&sB[(tx + 16 * j) * 68 + k];
#pragma unroll
        for (int i = 0; i < 4; i++)
#pragma unroll
            for (int j = 0; j < 4; j++) {
                acc[i][j] += av[i].x * bv[j].x;
                acc[i][j] += av[i].y * bv[j].y;
                acc[i][j] += av[i].z * bv[j].z;
                acc[i][j] += av[i].w * bv[j].w;
            }
    }
#pragma unroll
    for (int i = 0; i < 4; i++) {
        size_t row = (size_t)by * 64 + ty + 16 * i;
#pragma unroll
        for (int j = 0; j < 4; j++) {
            int col = bx * 64 + tx + 16 * j;
            C[row * 256 + col] = acc[i][j] + bias[col];
        }
    }
}

// ---------------- fused gx GEMM (m = relu(agg+rootC+cb) staged) + GRU update ----------------
__global__ __launch_bounds__(256) void k_gxgru(const float* __restrict__ agg,
                                               const float* __restrict__ rgh,
                                               const float* __restrict__ cb,
                                               const float* __restrict__ wih,   // gru_w_ih [192][64]
                                               const float* __restrict__ bih,
                                               float* __restrict__ outN) {
    __shared__ float sA[64 * 68];
    __shared__ float sB[192 * 68];
    const int t = threadIdx.x;
    const int by = blockIdx.x;
    for (int fi = t; fi < 64 * 16; fi += 256) {
        int r = fi >> 4, c = (fi & 15) * 4;
        float4 av = *(const float4*)(agg + (size_t)(by * 64 + r) * 64 + c);
        float4 rv = *(const float4*)(rgh + (size_t)(by * 64 + r) * 256 + c);
        float4 cv = *(const float4*)(cb + c);
        float4 m;
        m.x = fmaxf(av.x + rv.x + cv.x, 0.0f);
        m.y = fmaxf(av.y + rv.y + cv.y, 0.0f);
        m.z = fmaxf(av.z + rv.z + cv.z, 0.0f);
        m.w = fmaxf(av.w + rv.w + cv.w, 0.0f);
        *(float4*)&sA[r * 68 + c] = m;
    }
    for (int fi = t; fi < 192 * 16; fi += 256) {
        int r = fi >> 4, c = (fi & 15) * 4;
        *(float4*)&sB[r * 68 + c] = *(const float4*)(wih + (size_t)r * 64 + c);
    }
    __syncthreads();
    const int tx = t & 15, ty = t >> 4;
    float acc[3][4][4];
#pragma unroll
    for (int cx = 0; cx < 3; cx++)
#pragma unroll
        for (int i = 0; i < 4; i++)
#pragma unroll
            for (int j = 0; j < 4; j++) acc[cx][i][j] = 0.0f;
    for (int k = 0; k < 64; k += 4) {
        float4 av[4];
#pragma unroll
        for (int i = 0; i < 4; i++) av[i] = *(const float4*)&sA[(ty + 16 * i) * 68 + k];
#pragma unroll
        for (int cx = 0; cx < 3; cx++) {
            float4 bv[4];
#pragma unroll
            for (int j = 0; j < 4; j++) bv[j] = *(const float4*)&sB[(cx * 64 + tx + 16 * j) * 68 + k];
#pragma unroll
            for (int i = 0; i < 4; i++)
#pragma unroll
                for (int j = 0; j < 4; j++) {
                    acc[cx][i][j] += av[i].x * bv[j].x;
                    acc[cx][i][j] += av[i].y * bv[j].y;
                    acc[cx][i][j] += av[i].z * bv[j].z;
                    acc[cx][i][j] += av[i].w * bv[j].w;
                }
        }
    }
#pragma unroll
    for (int i = 0; i < 4; i++) {
        int n = by * 64 + ty + 16 * i;
        const float* ghr = rgh + (size_t)n * 256 + 64;
#pragma unroll
        for (int j = 0; j < 4; j++) {
            int d = tx + 16 * j;
            float r = sigmoidf_(acc[0][i][j] + bih[d] + ghr[d]);
            float z = sigmoidf_(acc[1][i][j] + bih[64 + d] + ghr[64 + d]);
            float nn_ = tanhf(acc[2][i][j] + bih[128 + d] + r * ghr[128 + d]);
            float hp = outN[(size_t)n * 64 + d];
            outN[(size_t)n * 64 + d] = (1.0f - z) * nn_ + z * hp;
        }
    }
}

// ---------------- fused Set2Set (3 steps) + head: one block per graph ----------------
__global__ __launch_bounds__(256) void k_s2sall(const float* __restrict__ outN,
                                                const int* __restrict__ offs,
                                                const float* __restrict__ wihT,
                                                const float* __restrict__ whhT,
                                                const float* __restrict__ bih,
                                                const float* __restrict__ bhh,
                                                const float* __restrict__ lin1_w,
                                                const float* __restrict__ lin1_b,
                                                const float* __restrict__ lin2_w,
                                                const float* __restrict__ lin2_b,
                                                float* __restrict__ earr,
                                                float* __restrict__ y) {
    const int b = blockIdx.x, t = threadIdx.x;
    const int w = t >> 6, l = t & 63;
    __shared__ float qs[128], qhL[64], qcL[64], gates[256];
    __shared__ float red[8];
    __shared__ float rpart[4][64];
    __shared__ float hbuf[64];
    const int s0 = offs[b], s1 = offs[b + 1];
    if (t < 128) qs[t] = 0.0f;
    if (t < 64) { qhL[t] = 0.0f; qcL[t] = 0.0f; }
    __syncthreads();

    for (int st = 0; st < 3; st++) {
        // LSTM gates (256 outputs, coalesced transposed weights)
        float g = bih[t] + bhh[t];
        for (int k = 0; k < 128; k++) g += qs[k] * wihT[k * 256 + t];
        for (int k = 0; k < 64; k++) g += qhL[k] * whhT[k * 256 + t];
        gates[t] = g;
        __syncthreads();
        if (t < 64) {
            float gi = gates[t], gf = gates[64 + t], gg = gates[128 + t], go = gates[192 + t];
            float c = sigmoidf_(gf) * qcL[t] + sigmoidf_(gi) * tanhf(gg);
            qcL[t] = c;
            qhL[t] = sigmoidf_(go) * tanhf(c);
        }
        __syncthreads();
        // e[i] = dot(out[i], qh); wave w handles nodes s0+w, s0+w+4, ...
        float mx = -INFINITY;
        for (int i = s0 + w; i < s1; i += 4) {
            float p = outN[(size_t)i * 64 + l] * qhL[l];
#pragma unroll
            for (int o = 32; o > 0; o >>= 1) p += __shfl_xor(p, o, 64);
            if (l == 0) earr[i] = p;
            mx = fmaxf(mx, p);
        }
        if (l == 0) red[w] = mx;
        __syncthreads();
        mx = fmaxf(fmaxf(red[0], red[1]), fmaxf(red[2], red[3]));
        if (!isfinite(mx)) mx = 0.0f;
        // sum + weighted node sum
        float sm = 0.0f, racc = 0.0f;
        for (int i = s0 + w; i < s1; i += 4) {
            float a = expf(earr[i] - mx);
            sm += a;
            racc += a * outN[(size_t)i * 64 + l];
        }
        rpart[w][l] = racc;
        if (l == 0) red[4 + w] = sm;
        __syncthreads();
        float smT = fmaxf(red[4] + red[5] + red[6] + red[7], 1e-12f);
        if (t < 64) {
            float r = (rpart[0][t] + rpart[1][t] + rpart[2][t] + rpart[3][t]) / smT;
            qs[t] = qhL[t];
            qs[64 + t] = r;
        }
        __syncthreads();
    }
    // head: y = relu(qs @ lin1.T + b1) @ lin2.T + b2
    if (t < 64) {
        float h = lin1_b[t];
        for (int k = 0; k < 128; k++) h += qs[k] * lin1_w[t * 128 + k];
        hbuf[t] = fmaxf(h, 0.0f) * lin2_w[t];
    }
    __syncthreads();
    if (w == 0) {
        float p = hbuf[l];
#pragma unroll
        for (int o = 32; o > 0; o >>= 1) p += __shfl_xor(p, o, 64);
        if (l == 0) y[b] = p + lin2_b[0];
    }
}

extern "C" void kernel_launch(void* const* d_in, const int* in_sizes, int n_in,
                              void* d_out, int out_size, void* d_ws, size_t ws_size,
                              hipStream_t stream) {
    const float* x = (const float*)d_in[0];
    const float* edge_attr = (const float*)d_in[1];
    const float* lin0_w = (const float*)d_in[2];
    const float* lin0_b = (const float*)d_in[3];
    const float* nn1_w = (const float*)d_in[4];
    const float* nn1_b = (const float*)d_in[5];
    const float* nn2_w = (const float*)d_in[6];
    const float* nn2_b = (const float*)d_in[7];
    const float* root_w = (const float*)d_in[8];
    const float* conv_b = (const float*)d_in[9];
    const float* gru_w_ih = (const float*)d_in[10];
    const float* gru_w_hh = (const float*)d_in[11];
    const float* gru_b_ih = (const float*)d_in[12];
    const float* gru_b_hh = (const float*)d_in[13];
    const float* s2s_w_ih = (const float*)d_in[14];
    const float* s2s_w_hh = (const float*)d_in[15];
    const float* s2s_b_ih = (const float*)d_in[16];
    const float* s2s_b_hh = (const float*)d_in[17];
    const float* lin1_w = (const float*)d_in[18];
    const float* lin1_b = (const float*)d_in[19];
    const float* lin2_w = (const float*)d_in[20];
    const float* lin2_b = (const float*)d_in[21];
    const int* ei = (const int*)d_in[22];
    const int* batch = (const int*)d_in[23];
    float* outp = (float*)d_out;

    char* w = (char*)d_ws;
    auto carve = [&](size_t bytes) { char* p = w; w += (bytes + 255) & ~(size_t)255; return p; };
    __hip_bfloat16* nn2bf = (__hip_bfloat16*)carve((size_t)4096 * 128 * 2);
    float* outN = (float*)carve((size_t)NN * 64 * 4);
    __hip_bfloat16* h1 = (__hip_bfloat16*)carve((size_t)EE * 128 * 2);
    int* deg = (int*)carve(NN * 4);
    float* invd = (float*)carve(NN * 4);
    float* agg = (float*)carve((size_t)NN * 64 * 4);
    float* rgh = (float*)carve((size_t)NN * 256 * 4);
    float* Bcat = (float*)carve((size_t)256 * 64 * 4);
    float* bcat = (float*)carve(256 * 4);
    float* wihT = (float*)carve((size_t)128 * 256 * 4);
    float* whhT = (float*)carve((size_t)64 * 256 * 4);
    float* earr = (float*)carve(NN * 4);
    int* cnt = (int*)carve(256 * 4);
    int* offs = (int*)carve(257 * 4);

    hipMemsetAsync(deg, 0, NN * 4, stream);
    hipMemsetAsync(cnt, 0, 256 * 4, stream);

    k_cast<<<512, 256, 0, stream>>>(nn2_w, nn2bf);
    k_prep<<<64, 256, 0, stream>>>(root_w, gru_w_hh, gru_b_hh, Bcat, bcat);
    k_tw<<<192, 256, 0, stream>>>(s2s_w_ih, s2s_w_hh, wihT, whhT);
    k_lin0<<<NN * 64 / 256, 256, 0, stream>>>(x, lin0_w, lin0_b, outN);
    k_h1<<<EE * 128 / 256, 256, 0, stream>>>(edge_attr, nn1_w, nn1_b, h1);
    k_counts<<<EE / 256, 256, 0, stream>>>(ei, batch, deg, cnt);
    k_inv<<<NN / 256, 256, 0, stream>>>(deg, invd);
    k_scan<<<1, 256, 0, stream>>>(cnt, offs);

    for (int it = 0; it < 3; it++) {
        k_rgh<<<dim3(4, NN / 64), 256, 0, stream>>>(outN, Bcat, bcat, rgh, agg);
        k_wemsg<<<EE / 64, 256, 0, stream>>>(h1, nn2bf, nn2_b, outN, ei, invd, agg);
        k_gxgru<<<NN / 64, 256, 0, stream>>>(agg, rgh, conv_b, gru_w_ih, gru_b_ih, outN);
    }

    k_s2sall<<<BB, 256, 0, stream>>>(outN, offs, wihT, whhT, s2s_b_ih, s2s_b_hh,
                                     lin1_w, lin1_b, lin2_w, lin2_b, earr, outp);
}

// Round 5
// 347.830 us; speedup vs baseline: 2.3344x; 1.0905x over previous
//
#include <hip/hip_runtime.h>
#include <hip/hip_bf16.h>
#include <stdint.h>

#define NN 8192
#define EE 32768
#define BB 256
#define DD 64
#define FIN 11
#define EIN 5
#define HH 128

typedef __attribute__((ext_vector_type(4))) float f32x4;
typedef __attribute__((ext_vector_type(8))) short bf16x8;

__device__ __forceinline__ float sigmoidf_(float x) { return 1.0f / (1.0f + expf(-x)); }

__device__ __forceinline__ void gload16(const void* g, void* l) {
    __builtin_amdgcn_global_load_lds(
        (const __attribute__((address_space(1))) unsigned int*)g,
        (__attribute__((address_space(3))) unsigned int*)l, 16, 0, 0);
}

// ---------------- cast nn2_w -> bf16 (natural layout [j=d*64+f][k]) ----------------
__global__ __launch_bounds__(256) void k_cast(const float* __restrict__ src,
                                              __hip_bfloat16* __restrict__ dst) {
    int i = (blockIdx.x * 256 + threadIdx.x) * 4;     // over 4096*128
    float4 v = *(const float4*)(src + i);
    ushort4 o;
    __hip_bfloat16 b0 = __float2bfloat16(v.x); o.x = *(ushort*)&b0;
    __hip_bfloat16 b1 = __float2bfloat16(v.y); o.y = *(ushort*)&b1;
    __hip_bfloat16 b2 = __float2bfloat16(v.z); o.z = *(ushort*)&b2;
    __hip_bfloat16 b3 = __float2bfloat16(v.w); o.w = *(ushort*)&b3;
    *(ushort4*)((ushort*)dst + i) = o;
}

// ---- prepack Bcat = [root_w(64) ; gru_w_hh(192) ; bmatT(64)], bcat = [0 ; gru_b_hh ; 0] ----
// bmatT row (256+f), col d = nn2_b[d*64+f]  (nodeBias GEMM weights)
__global__ __launch_bounds__(256) void k_prep(const float* __restrict__ root_w,
                                              const float* __restrict__ whh,
                                              const float* __restrict__ bhh,
                                              const float* __restrict__ nn2b,
                                              float* __restrict__ Bcat,
                                              float* __restrict__ bcat) {
    int i = blockIdx.x * 256 + threadIdx.x;           // over 320*64
    int r = i >> 6, c = i & 63;
    float v;
    if (r < 64) v = root_w[i];
    else if (r < 256) v = whh[(size_t)(r - 64) * 64 + c];
    else v = nn2b[c * 64 + (r - 256)];
    Bcat[i] = v;
    if (c == 0) bcat[r] = (r >= 64 && r < 256) ? bhh[r - 64] : 0.0f;
}

// ---------------- transpose s2s weights ----------------
__global__ __launch_bounds__(256) void k_tw(const float* __restrict__ wih,
                                            const float* __restrict__ whh,
                                            float* __restrict__ wihT,
                                            float* __restrict__ whhT) {
    int i = blockIdx.x * 256 + threadIdx.x;           // 32768 + 16384
    if (i < 256 * 128) {
        int j = i >> 7, k = i & 127;
        wihT[k * 256 + j] = wih[i];
    } else {
        int i2 = i - 256 * 128;
        if (i2 < 256 * 64) {
            int j = i2 >> 6, k = i2 & 63;
            whhT[k * 256 + j] = whh[i2];
        }
    }
}

// ---------------- lin0 ----------------
__global__ __launch_bounds__(256) void k_lin0(const float* __restrict__ x,
                                              const float* __restrict__ w,
                                              const float* __restrict__ b,
                                              float* __restrict__ out) {
    int idx = blockIdx.x * 256 + threadIdx.x;         // over N*64
    int n = idx >> 6, d = idx & 63;
    float a = b[d];
#pragma unroll
    for (int k = 0; k < FIN; k++) a += x[n * FIN + k] * w[d * FIN + k];
    out[idx] = fmaxf(a, 0.0f);
}

// ---------------- h1 -> bf16 ----------------
__global__ __launch_bounds__(256) void k_h1(const float* __restrict__ ea,
                                            const float* __restrict__ w,
                                            const float* __restrict__ b,
                                            __hip_bfloat16* __restrict__ h1) {
    int idx = blockIdx.x * 256 + threadIdx.x;         // over E*128
    int e = idx >> 7, k = idx & 127;
    float a = b[k];
#pragma unroll
    for (int j = 0; j < EIN; j++) a += ea[e * EIN + j] * w[k * EIN + j];
    h1[idx] = __float2bfloat16(fmaxf(a, 0.0f));
}

// ---------------- degree count + batch count (merged) ----------------
__global__ __launch_bounds__(256) void k_counts(const int* __restrict__ ei,
                                                const int* __restrict__ batch,
                                                int* __restrict__ deg,
                                                int* __restrict__ cnt) {
    int i = blockIdx.x * 256 + threadIdx.x;
    if (i < EE) atomicAdd(&deg[ei[EE + i]], 1);
    if (i < NN) atomicAdd(&cnt[batch[i]], 1);
}
__global__ __launch_bounds__(256) void k_inv(const int* __restrict__ deg, float* __restrict__ invd) {
    int n = blockIdx.x * 256 + threadIdx.x;
    if (n < NN) { int d = deg[n]; invd[n] = d > 0 ? 1.0f / (float)d : 0.0f; }
}
__global__ __launch_bounds__(256) void k_scan(const int* __restrict__ cnt, int* __restrict__ offs) {
    __shared__ int s[256];
    int t = threadIdx.x;
    s[t] = cnt[t];
    __syncthreads();
    for (int off = 1; off < 256; off <<= 1) {
        int v = (t >= off) ? s[t - off] : 0;
        __syncthreads();
        s[t] += v;
        __syncthreads();
    }
    offs[t + 1] = s[t];
    if (t == 0) offs[0] = 0;
}

// ---------------- fused NNConv message pass, register-A + double-buffered B ----------------
// Block = 64 edges. 64 chunks, chunk d = nn2 rows j=d*64..d*64+63 (one d, all 64 f).
// Wave w owns f-slice w*16+l15. A-frags (h1) in registers; B chunk staged to LDS (dbuf);
// msg[e][f] += MFMA(h1,nn2)[e, f] * soT[d][e]; bias via precomputed nodeB gathered per edge.
__global__ __launch_bounds__(256) void k_wemsg(const __hip_bfloat16* __restrict__ h1,
                                               const __hip_bfloat16* __restrict__ nn2bf,
                                               const float* __restrict__ outN,
                                               const float* __restrict__ rgh,  // nodeB at col 256, stride 320
                                               const int* __restrict__ ei,
                                               const float* __restrict__ invd,
                                               float* __restrict__ agg) {
    __shared__ ushort sB[2][64 * 128];  // 32 KB, swizzled chunk dbuf
    __shared__ float soT[64 * 64];      // 16 KB  [d][e]
    __shared__ float snbT[64 * 64];     // 16 KB  [f][e]
    __shared__ int sDst[64];
    __shared__ float sIv[64];

    const int t = threadIdx.x;
    const int w = t >> 6, l = t & 63;
    const int q = l >> 4, l15 = l & 15;
    const int e0 = blockIdx.x * 64;

    // ---- prologue: gather out[src] and nodeB[src] rows, transposed ----
    {
        int r = t >> 2, seg = t & 3;
        int s_ = ei[e0 + r];
        const float* orow = outN + (size_t)s_ * 64 + seg * 16;
        const float* nrow = rgh + (size_t)s_ * 320 + 256 + seg * 16;
#pragma unroll
        for (int i = 0; i < 4; i++) {
            float4 v = *(const float4*)(orow + i * 4);
            float4 nb = *(const float4*)(nrow + i * 4);
            int c0 = seg * 16 + i * 4;
            soT[(c0 + 0) * 64 + r] = v.x;
            soT[(c0 + 1) * 64 + r] = v.y;
            soT[(c0 + 2) * 64 + r] = v.z;
            soT[(c0 + 3) * 64 + r] = v.w;
            snbT[(c0 + 0) * 64 + r] = nb.x;
            snbT[(c0 + 1) * 64 + r] = nb.y;
            snbT[(c0 + 2) * 64 + r] = nb.z;
            snbT[(c0 + 3) * 64 + r] = nb.w;
        }
        if (seg == 0) {
            int d_ = ei[EE + e0 + r];
            sDst[r] = d_;
            sIv[r] = invd[d_];
        }
    }
    // ---- A fragments to registers (each wave loads the full 64-edge tile) ----
    bf16x8 af[4][4];
#pragma unroll
    for (int mi = 0; mi < 4; mi++)
#pragma unroll
        for (int kk = 0; kk < 4; kk++)
            af[mi][kk] = *(const bf16x8*)(h1 + (size_t)(e0 + mi * 16 + l15) * 128 + (kk * 4 + q) * 8);

    // ---- stage chunk 0 into sB[0] (1024 16B units, inverse-swizzled source) ----
#pragma unroll
    for (int i = 0; i < 4; i++) {
        int u = i * 256 + t;
        int r = u >> 4, c = u & 15, cs = c ^ (r & 7);
        gload16(nn2bf + ((size_t)r * 128 + cs * 8), &sB[0][(i * 256 + w * 64) * 8]);
    }
    __syncthreads();

    float msg[4][4];
#pragma unroll
    for (int mi = 0; mi < 4; mi++)
#pragma unroll
        for (int j = 0; j < 4; j++) msg[mi][j] = 0.0f;

    for (int d = 0; d < 64; ++d) {
        const int cur = d & 1;
        if (d < 63) {   // prefetch next chunk into the other buffer
#pragma unroll
            for (int i = 0; i < 4; i++) {
                int u = i * 256 + t;
                int r = u >> 4, c = u & 15, cs = c ^ (r & 7);
                gload16(nn2bf + ((size_t)((d + 1) * 64 + r) * 128 + cs * 8),
                        &sB[cur ^ 1][(i * 256 + w * 64) * 8]);
            }
        }
        const ushort* sbc = &sB[cur][0];
        f32x4 acc[4];
#pragma unroll
        for (int mi = 0; mi < 4; mi++) acc[mi] = (f32x4)0.0f;
        const int rb = w * 16 + l15;
#pragma unroll
        for (int kk = 0; kk < 4; kk++) {
            bf16x8 bfr = *(const bf16x8*)&sbc[(rb * 16 + ((kk * 4 + q) ^ (rb & 7))) * 8];
#pragma unroll
            for (int mi = 0; mi < 4; mi++)
                acc[mi] = __builtin_amdgcn_mfma_f32_16x16x32_bf16(af[mi][kk], bfr, acc[mi], 0, 0, 0);
        }
#pragma unroll
        for (int mi = 0; mi < 4; mi++) {
            f32x4 sov = *(const f32x4*)&soT[d * 64 + mi * 16 + q * 4];
#pragma unroll
            for (int j = 0; j < 4; j++) msg[mi][j] += acc[mi][j] * sov[j];
        }
        __syncthreads();   // all waves done with sB[cur]; prefetch (vmcnt) drained
    }

    // ---- add bias term (nodeB) and scatter with inv_deg ----
#pragma unroll
    for (int mi = 0; mi < 4; mi++) {
        f32x4 nb = *(const f32x4*)&snbT[(w * 16 + l15) * 64 + mi * 16 + q * 4];
#pragma unroll
        for (int j = 0; j < 4; j++) {
            int er = mi * 16 + q * 4 + j;
            atomicAdd(&agg[(size_t)sDst[er] * 64 + w * 16 + l15], (msg[mi][j] + nb[j]) * sIv[er]);
        }
    }
}

// ---------------- rgh = outN @ Bcat.T + bcat  [N][320]; also zeroes agg ----------------
__global__ __launch_bounds__(256) void k_rgh(const float* __restrict__ A,
                                             const float* __restrict__ Bm,
                                             const float* __restrict__ bias,
                                             float* __restrict__ C,
                                             float* __restrict__ aggz) {
    const int tid = threadIdx.x;
    const int bx = blockIdx.x, by = blockIdx.y;   // grid (5, 128)
    {
        int bid = by * 5 + bx;
        if (bid < 512) {
            float4 z; z.x = z.y = z.z = z.w = 0.0f;
            *(float4*)(aggz + (size_t)bid * 1024 + tid * 4) = z;
        }
    }
    __shared__ float sA[64 * 68];
    __shared__ float sB[64 * 68];
    const float* Ab = A + (size_t)by * 64 * 64;
    const float* Bb = Bm + (size_t)bx * 64 * 64;
    for (int fi = tid; fi < 64 * 16; fi += 256) {
        int r = fi >> 4, c = (fi & 15) * 4;
        *(float4*)&sA[r * 68 + c] = *(const float4*)(Ab + (size_t)r * 64 + c);
        *(float4*)&sB[r * 68 + c] = *(const float4*)(Bb + (size_t)r * 64 + c);
    }
    __syncthreads();
    const int tx = tid & 15, ty = tid >> 4;
    float acc[4][4];
#pragma unroll
    for (int i = 0; i < 4; i++)
#pragma unroll
        for (int j = 0; j < 4; j++) acc[i][j] = 0.0f;
    for (int k = 0; k < 64; k += 4) {
        float4 av[4], bv[4];
#pragma unroll
        for (int i = 0; i < 4; i++) av[i] = *(const float4*)&sA[(ty + 16 * i) * 68 + k];
#pragma unroll
        for (int j = 0; j < 4; j++) bv[j] = *(const float4*)&sB[(tx + 16 * j) * 68 + k];
#pragma unroll
        for (int i = 0; i < 4; i++)
#pragma unroll
            for (int j = 0; j < 4; j++) {
                acc[i][j] += av[i].x * bv[j].x;
                acc[i][j] += av[i].y * bv[j].y;
                acc[i][j] += av[i].z * bv[j].z;
                acc[i][j] += av[i].w * bv[j].w;
            }
    }
#pragma unroll
    for (int i = 0; i < 4; i++) {
        size_t row = (size_t)by * 64 + ty + 16 * i;
#pragma unroll
        for (int j = 0; j < 4; j++) {
            int col = bx * 64 + tx + 16 * j;
            C[row * 320 + col] = acc[i][j] + bias[col];
        }
    }
}

// ---------------- fused gx GEMM (m = relu(agg+rootC+cb) staged) + GRU update ----------------
__global__ __launch_bounds__(256) void k_gxgru(const float* __restrict__ agg,
                                               const float* __restrict__ rgh,
                                               const float* __restrict__ cb,
                                               const float* __restrict__ wih,   // gru_w_ih [192][64]
                                               const float* __restrict__ bih,
                                               float* __restrict__ outN) {
    __shared__ float sA[64 * 68];
    __shared__ float sB[192 * 68];
    const int t = threadIdx.x;
    const int by = blockIdx.x;
    for (int fi = t; fi < 64 * 16; fi += 256) {
        int r = fi >> 4, c = (fi & 15) * 4;
        float4 av = *(const float4*)(agg + (size_t)(by * 64 + r) * 64 + c);
        float4 rv = *(const float4*)(rgh + (size_t)(by * 64 + r) * 320 + c);
        float4 cv = *(const float4*)(cb + c);
        float4 m;
        m.x = fmaxf(av.x + rv.x + cv.x, 0.0f);
        m.y = fmaxf(av.y + rv.y + cv.y, 0.0f);
        m.z = fmaxf(av.z + rv.z + cv.z, 0.0f);
        m.w = fmaxf(av.w + rv.w + cv.w, 0.0f);
        *(float4*)&sA[r * 68 + c] = m;
    }
    for (int fi = t; fi < 192 * 16; fi += 256) {
        int r = fi >> 4, c = (fi & 15) * 4;
        *(float4*)&sB[r * 68 + c] = *(const float4*)(wih + (size_t)r * 64 + c);
    }
    __syncthreads();
    const int tx = t & 15, ty = t >> 4;
    float acc[3][4][4];
#pragma unroll
    for (int cx = 0; cx < 3; cx++)
#pragma unroll
        for (int i = 0; i < 4; i++)
#pragma unroll
            for (int j = 0; j < 4; j++) acc[cx][i][j] = 0.0f;
    for (int k = 0; k < 64; k += 4) {
        float4 av[4];
#pragma unroll
        for (int i = 0; i < 4; i++) av[i] = *(const float4*)&sA[(ty + 16 * i) * 68 + k];
#pragma unroll
        for (int cx = 0; cx < 3; cx++) {
            float4 bv[4];
#pragma unroll
            for (int j = 0; j < 4; j++) bv[j] = *(const float4*)&sB[(cx * 64 + tx + 16 * j) * 68 + k];
#pragma unroll
            for (int i = 0; i < 4; i++)
#pragma unroll
                for (int j = 0; j < 4; j++) {
                    acc[cx][i][j] += av[i].x * bv[j].x;
                    acc[cx][i][j] += av[i].y * bv[j].y;
                    acc[cx][i][j] += av[i].z * bv[j].z;
                    acc[cx][i][j] += av[i].w * bv[j].w;
                }
        }
    }
#pragma unroll
    for (int i = 0; i < 4; i++) {
        int n = by * 64 + ty + 16 * i;
        const float* ghr = rgh + (size_t)n * 320 + 64;
#pragma unroll
        for (int j = 0; j < 4; j++) {
            int d = tx + 16 * j;
            float r = sigmoidf_(acc[0][i][j] + bih[d] + ghr[d]);
            float z = sigmoidf_(acc[1][i][j] + bih[64 + d] + ghr[64 + d]);
            float nn_ = tanhf(acc[2][i][j] + bih[128 + d] + r * ghr[128 + d]);
            float hp = outN[(size_t)n * 64 + d];
            outN[(size_t)n * 64 + d] = (1.0f - z) * nn_ + z * hp;
        }
    }
}

// ---------------- fused Set2Set (3 steps) + head: one block per graph ----------------
__global__ __launch_bounds__(256) void k_s2sall(const float* __restrict__ outN,
                                                const int* __restrict__ offs,
                                                const float* __restrict__ wihT,
                                                const float* __restrict__ whhT,
                                                const float* __restrict__ bih,
                                                const float* __restrict__ bhh,
                                                const float* __restrict__ lin1_w,
                                                const float* __restrict__ lin1_b,
                                                const float* __restrict__ lin2_w,
                                                const float* __restrict__ lin2_b,
                                                float* __restrict__ earr,
                                                float* __restrict__ y) {
    const int b = blockIdx.x, t = threadIdx.x;
    const int w = t >> 6, l = t & 63;
    __shared__ float qs[128], qhL[64], qcL[64], gates[256];
    __shared__ float red[8];
    __shared__ float rpart[4][64];
    __shared__ float hbuf[64];
    const int s0 = offs[b], s1 = offs[b + 1];
    if (t < 128) qs[t] = 0.0f;
    if (t < 64) { qhL[t] = 0.0f; qcL[t] = 0.0f; }
    __syncthreads();

    for (int st = 0; st < 3; st++) {
        float g = bih[t] + bhh[t];
        for (int k = 0; k < 128; k++) g += qs[k] * wihT[k * 256 + t];
        for (int k = 0; k < 64; k++) g += qhL[k] * whhT[k * 256 + t];
        gates[t] = g;
        __syncthreads();
        if (t < 64) {
            float gi = gates[t], gf = gates[64 + t], gg = gates[128 + t], go = gates[192 + t];
            float c = sigmoidf_(gf) * qcL[t] + sigmoidf_(gi) * tanhf(gg);
            qcL[t] = c;
            qhL[t] = sigmoidf_(go) * tanhf(c);
        }
        __syncthreads();
        float mx = -INFINITY;
        for (int i = s0 + w; i < s1; i += 4) {
            float p = outN[(size_t)i * 64 + l] * qhL[l];
#pragma unroll
            for (int o = 32; o > 0; o >>= 1) p += __shfl_xor(p, o, 64);
            if (l == 0) earr[i] = p;
            mx = fmaxf(mx, p);
        }
        if (l == 0) red[w] = mx;
        __syncthreads();
        mx = fmaxf(fmaxf(red[0], red[1]), fmaxf(red[2], red[3]));
        if (!isfinite(mx)) mx = 0.0f;
        float sm = 0.0f, racc = 0.0f;
        for (int i = s0 + w; i < s1; i += 4) {
            float a = expf(earr[i] - mx);
            sm += a;
            racc += a * outN[(size_t)i * 64 + l];
        }
        rpart[w][l] = racc;
        if (l == 0) red[4 + w] = sm;
        __syncthreads();
        float smT = fmaxf(red[4] + red[5] + red[6] + red[7], 1e-12f);
        if (t < 64) {
            float r = (rpart[0][t] + rpart[1][t] + rpart[2][t] + rpart[3][t]) / smT;
            qs[t] = qhL[t];
            qs[64 + t] = r;
        }
        __syncthreads();
    }
    if (t < 64) {
        float h = lin1_b[t];
        for (int k = 0; k < 128; k++) h += qs[k] * lin1_w[t * 128 + k];
        hbuf[t] = fmaxf(h, 0.0f) * lin2_w[t];
    }
    __syncthreads();
    if (w == 0) {
        float p = hbuf[l];
#pragma unroll
        for (int o = 32; o > 0; o >>= 1) p += __shfl_xor(p, o, 64);
        if (l == 0) y[b] = p + lin2_b[0];
    }
}

extern "C" void kernel_launch(void* const* d_in, const int* in_sizes, int n_in,
                              void* d_out, int out_size, void* d_ws, size_t ws_size,
                              hipStream_t stream) {
    const float* x = (const float*)d_in[0];
    const float* edge_attr = (const float*)d_in[1];
    const float* lin0_w = (const float*)d_in[2];
    const float* lin0_b = (const float*)d_in[3];
    const float* nn1_w = (const float*)d_in[4];
    const float* nn1_b = (const float*)d_in[5];
    const float* nn2_w = (const float*)d_in[6];
    const float* nn2_b = (const float*)d_in[7];
    const float* root_w = (const float*)d_in[8];
    const float* conv_b = (const float*)d_in[9];
    const float* gru_w_ih = (const float*)d_in[10];
    const float* gru_w_hh = (const float*)d_in[11];
    const float* gru_b_ih = (const float*)d_in[12];
    const float* gru_b_hh = (const float*)d_in[13];
    const float* s2s_w_ih = (const float*)d_in[14];
    const float* s2s_w_hh = (const float*)d_in[15];
    const float* s2s_b_ih = (const float*)d_in[16];
    const float* s2s_b_hh = (const float*)d_in[17];
    const float* lin1_w = (const float*)d_in[18];
    const float* lin1_b = (const float*)d_in[19];
    const float* lin2_w = (const float*)d_in[20];
    const float* lin2_b = (const float*)d_in[21];
    const int* ei = (const int*)d_in[22];
    const int* batch = (const int*)d_in[23];
    float* outp = (float*)d_out;

    char* w = (char*)d_ws;
    auto carve = [&](size_t bytes) { char* p = w; w += (bytes + 255) & ~(size_t)255; return p; };
    __hip_bfloat16* nn2bf = (__hip_bfloat16*)carve((size_t)4096 * 128 * 2);
    float* outN = (float*)carve((size_t)NN * 64 * 4);
    __hip_bfloat16* h1 = (__hip_bfloat16*)carve((size_t)EE * 128 * 2);
    int* deg = (int*)carve(NN * 4);
    float* invd = (float*)carve(NN * 4);
    float* agg = (float*)carve((size_t)NN * 64 * 4);
    float* rgh = (float*)carve((size_t)NN * 320 * 4);
    float* Bcat = (float*)carve((size_t)320 * 64 * 4);
    float* bcat = (float*)carve(320 * 4);
    float* wihT = (float*)carve((size_t)128 * 256 * 4);
    float* whhT = (float*)carve((size_t)64 * 256 * 4);
    float* earr = (float*)carve(NN * 4);
    int* cnt = (int*)carve(256 * 4);
    int* offs = (int*)carve(257 * 4);

    hipMemsetAsync(deg, 0, NN * 4, stream);
    hipMemsetAsync(cnt, 0, 256 * 4, stream);

    k_cast<<<512, 256, 0, stream>>>(nn2_w, nn2bf);
    k_prep<<<80, 256, 0, stream>>>(root_w, gru_w_hh, gru_b_hh, nn2_b, Bcat, bcat);
    k_tw<<<192, 256, 0, stream>>>(s2s_w_ih, s2s_w_hh, wihT, whhT);
    k_lin0<<<NN * 64 / 256, 256, 0, stream>>>(x, lin0_w, lin0_b, outN);
    k_h1<<<EE * 128 / 256, 256, 0, stream>>>(edge_attr, nn1_w, nn1_b, h1);
    k_counts<<<EE / 256, 256, 0, stream>>>(ei, batch, deg, cnt);
    k_inv<<<NN / 256, 256, 0, stream>>>(deg, invd);
    k_scan<<<1, 256, 0, stream>>>(cnt, offs);

    for (int it = 0; it < 3; it++) {
        k_rgh<<<dim3(5, NN / 64), 256, 0, stream>>>(outN, Bcat, bcat, rgh, agg);
        k_wemsg<<<EE / 64, 256, 0, stream>>>(h1, nn2bf, outN, rgh, ei, invd, agg);
        k_gxgru<<<NN / 64, 256, 0, stream>>>(agg, rgh, conv_b, gru_w_ih, gru_b_ih, outN);
    }

    k_s2sall<<<BB, 256, 0, stream>>>(outN, offs, wihT, whhT, s2s_b_ih, s2s_b_hh,
                                     lin1_w, lin1_b, lin2_w, lin2_b, earr, outp);
}